// Round 2
// baseline (344.332 us; speedup 1.0000x reference)
//
#include <hip/hip_runtime.h>
#include <hip/hip_bf16.h>

#define N_NODES 50000
#define N_EDGES 600000
#define D 128
#define BS 512
#define L 10
#define MAXS (BS*L + BS)   // 5632 max needed slots
#define NOUT 49999
#define NTILES 3125        // ceil(49999/16)
#define CAP 64             // per-slot edge bucket capacity (deg ~ Poisson(12))

// wT element offsets (bf16, (n,k) layout)
#define W1T 0        // 128 x 256
#define W3T 32768    // 128 x 128
#define G1T 49152
#define G2T 65536
#define G3T 81920
#define G4T 98304
#define WT_ELEMS 114688

typedef __attribute__((ext_vector_type(8))) short bf16x8;
typedef __attribute__((ext_vector_type(4))) float f32x4;

__device__ __forceinline__ unsigned short f2bf(float f){
  union { float f; unsigned int i; } v; v.f = f;
  unsigned int i = v.i;
  return (unsigned short)((i + 0x7fffu + ((i >> 16) & 1u)) >> 16);
}
__device__ __forceinline__ float sigm(float x){ return 1.f/(1.f+__expf(-x)); }
__device__ __forceinline__ float tanh_f(float x){
  x = fminf(fmaxf(x, -15.f), 15.f);
  float e = __expf(2.f*x);
  return (e-1.f)/(e+1.f);
}

// ---- K_prep: transpose+cvt weights to bf16 (n,k) layout; blocks 448..511 zero scratch ----
__global__ __launch_bounds__(256) void k_prep(const float* __restrict__ w1,
    const float* __restrict__ w3, const float* __restrict__ g1,
    const float* __restrict__ g2, const float* __restrict__ g3,
    const float* __restrict__ g4, unsigned short* __restrict__ wT,
    int* __restrict__ map, int* __restrict__ cursor, int* __restrict__ counters){
  int bid = blockIdx.x, tid = threadIdx.x;
  if (bid < 128){
    int e = bid*256 + tid;
    int k = e >> 7, n = e & 127;
    wT[W1T + n*256 + k] = f2bf(w1[e]);
  } else if (bid < 448){
    int mm = (bid - 128) >> 6;
    int e = ((bid - 128) & 63)*256 + tid;
    int k = e >> 7, n = e & 127;
    const float* src = (mm==0)? w3 : (mm==1)? g1 : (mm==2)? g2 : (mm==3)? g3 : g4;
    int dst = (mm==0)? W3T : (mm==1)? G1T : (mm==2)? G2T : (mm==3)? G3T : G4T;
    wT[dst + n*128 + k] = f2bf(src[e]);
  } else {
    // zero map (N_NODES), cursor (MAXS), counters (4)
    const int TOT = N_NODES + MAXS + 4;
    for (int idx = (bid-448)*256 + tid; idx < TOT; idx += 64*256){
      if (idx < N_NODES) map[idx] = 0;
      else if (idx < N_NODES + MAXS) cursor[idx - N_NODES] = 0;
      else counters[idx - N_NODES - MAXS] = 0;
    }
  }
}

// ---- K1: mark + compact fused; CAS winner allocates the slot ----
__global__ void k_markcompact(const int* __restrict__ seq, const int* __restrict__ user,
                              const int* __restrict__ item_num, int* __restrict__ map,
                              int* __restrict__ invmap, int* __restrict__ counters){
  int i = blockIdx.x*256 + threadIdx.x;
  int node = -1;
  if (i < BS*L) node = seq[i];
  else if (i < BS*L + BS) node = user[i - BS*L] + item_num[0];
  if (node >= 0){
    if (atomicCAS(&map[node], 0, 1) == 0){
      int s = atomicAdd(&counters[0], 1);
      invmap[s] = node;
      map[node] = s + 2;
    }
  }
}

// ---- K2: single-pass scatter into fixed-capacity buckets; cursor = degree ----
__global__ void k_scatter(const int* __restrict__ esrc, const int* __restrict__ edst,
                          const int* __restrict__ map, int* __restrict__ cursor,
                          int* __restrict__ bucket){
  for (int e = blockIdx.x*blockDim.x + threadIdx.x; e < N_EDGES; e += gridDim.x*blockDim.x){
    int mv = map[edst[e]];
    if (mv >= 2){
      int slot = mv - 2;
      int pos = atomicAdd(&cursor[slot], 1);
      if (pos < CAP) bucket[slot*CAP + pos] = esrc[e];
    }
  }
}

// ---- K2d: per-slot gather-sum -> neigh = agg/max(deg,1) ----
__global__ void k_neigh(const float* __restrict__ v2e, const int* __restrict__ bucket,
                        const int* __restrict__ cursor, const int* __restrict__ counters,
                        float* __restrict__ neigh){
  int s = blockIdx.x; int t = threadIdx.x;
  if (s >= counters[0]) return;
  int deg = cursor[s];
  int cnt = min(deg, CAP);
  float acc = 0.f;
  for (int j=0;j<cnt;j++){
    int src = bucket[s*CAP + j];
    acc += v2e[(size_t)src*D + t];
  }
  neigh[(size_t)s*D + t] = acc / fmaxf((float)deg, 1.0f);
}

// ---- K3: h1 for needed slots only (8 slots/block) ----
#define SL8 8
__global__ __launch_bounds__(128) void k_h1(const float* __restrict__ v2e,
                     const float* __restrict__ neigh, const int* __restrict__ invmap,
                     const int* __restrict__ counters, const float* __restrict__ Wself,
                     const float* __restrict__ Wneigh, const float* __restrict__ bsage,
                     float* __restrict__ h1c){
  __shared__ float vv[SL8][D];
  __shared__ float nn[SL8][D];
  int t = threadIdx.x;
  int nslots = counters[0];
  int sb = blockIdx.x*SL8;
  for (int i=0;i<SL8;i++){
    int s = sb+i;
    if (s < nslots){
      int node = invmap[s];
      vv[i][t] = v2e[(size_t)node*D + t];
      nn[i][t] = neigh[(size_t)s*D + t];
    }
  }
  __syncthreads();
  float bias = bsage[t];
  float acc[SL8];
  #pragma unroll
  for (int i=0;i<SL8;i++) acc[i] = bias;
  for (int k=0;k<D;k++){
    float ws = Wself[k*D + t];
    float wn = Wneigh[k*D + t];
    #pragma unroll
    for (int i=0;i<SL8;i++) acc[i] += vv[i][k]*ws + nn[i][k]*wn;
  }
  for (int i=0;i<SL8;i++){
    int s = sb+i;
    if (s < nslots) h1c[(size_t)s*D + t] = fmaxf(acc[i], 0.f);
  }
}

// ---- K4a: gather ie/pe/ue/avg; build bf16 A-matrices ----
__global__ __launch_bounds__(128) void k4a(const int* __restrict__ user, const int* __restrict__ seq,
    const int* __restrict__ mask, const int* __restrict__ pos_idx, const int* __restrict__ item_num,
    const int* __restrict__ map, const float* __restrict__ h1c, const float* __restrict__ v2e,
    const float* __restrict__ pos_w, float* __restrict__ ie, float* __restrict__ ue,
    unsigned short* __restrict__ Xcat, unsigned short* __restrict__ AU){
  int b = blockIdx.x, t = threadIdx.x;
  float av = 0.f, msum = 0.f;
  for (int l=0;l<L;l++){
    int node = seq[b*L+l];
    int slot = map[node]-2;
    float v = 0.5f*(h1c[(size_t)slot*D+t] + v2e[(size_t)node*D+t]);
    ie[(size_t)(b*L+l)*D+t] = v;
    Xcat[(size_t)(b*L+l)*256 + 128 + t] = f2bf(v);
    int p = pos_idx[b*L+l];
    Xcat[(size_t)(b*L+l)*256 + t] = f2bf(pos_w[(size_t)p*D+t]);
    float m = (float)mask[b*L+l];
    av += v*m; msum += m;
  }
  AU[(size_t)b*D+t] = f2bf(av/msum);
  int unode = user[b]+item_num[0];
  int uslot = map[unode]-2;
  float uv = 0.5f*(h1c[(size_t)uslot*D+t] + v2e[(size_t)unode*D+t]);
  ue[(size_t)b*D+t] = uv;
  AU[(size_t)(512+b)*D+t] = f2bf(uv);
}

// ---- K4bc: blocks 0..319: nh1/nh2 GEMMs. blocks 320..383: g24 GEMM. ----
__global__ __launch_bounds__(256) void k4bc(const unsigned short* __restrict__ Xcat,
    const unsigned short* __restrict__ AU, const unsigned short* __restrict__ wT,
    unsigned short* __restrict__ nh1, unsigned short* __restrict__ nh2,
    float* __restrict__ g24){
  int wv = threadIdx.x>>6, lane = threadIdx.x&63;
  int r = lane&15, q = lane>>4;
  if (blockIdx.x < 320){
    int mt = blockIdx.x;
    const bf16x8* Arow = (const bf16x8*)(Xcat + (size_t)(mt*16+r)*256 + q*8);
    bf16x8 a[8];
    #pragma unroll
    for (int kf=0;kf<8;kf++) a[kf] = Arow[kf*4];
    #pragma unroll
    for (int i=0;i<2;i++){   // nh1, K=256
      int nt = wv + 4*i;
      const bf16x8* Brow = (const bf16x8*)(wT + W1T + (size_t)(nt*16+r)*256 + q*8);
      f32x4 acc = {0.f,0.f,0.f,0.f};
      #pragma unroll
      for (int kf=0;kf<8;kf++)
        acc = __builtin_amdgcn_mfma_f32_16x16x32_bf16(a[kf], Brow[kf*4], acc, 0,0,0);
      #pragma unroll
      for (int g=0; g<4; g++)
        nh1[(size_t)(mt*16 + q*4 + g)*128 + nt*16 + r] = f2bf(tanh_f(acc[g]));
    }
    #pragma unroll
    for (int i=0;i<2;i++){   // nh2, K=128 (ie = Xcat cols 128..255 -> a[4..7])
      int nt = wv + 4*i;
      const bf16x8* Brow = (const bf16x8*)(wT + W3T + (size_t)(nt*16+r)*128 + q*8);
      f32x4 acc = {0.f,0.f,0.f,0.f};
      #pragma unroll
      for (int kf=0;kf<4;kf++)
        acc = __builtin_amdgcn_mfma_f32_16x16x32_bf16(a[4+kf], Brow[kf*4], acc, 0,0,0);
      #pragma unroll
      for (int g=0; g<4; g++)
        nh2[(size_t)(mt*16 + q*4 + g)*128 + nt*16 + r] = f2bf(tanh_f(acc[g]));
    }
  } else {
    int mt = blockIdx.x - 320;  // 0..63
    const unsigned short* Bbase = wT + ((mt*16 >= 512) ? G4T : G2T);
    const bf16x8* Arow = (const bf16x8*)(AU + (size_t)(mt*16+r)*128 + q*8);
    bf16x8 a[4];
    #pragma unroll
    for (int kf=0;kf<4;kf++) a[kf] = Arow[kf*4];
    #pragma unroll
    for (int i=0;i<2;i++){
      int nt = wv + 4*i;
      const bf16x8* Brow = (const bf16x8*)(Bbase + (size_t)(nt*16+r)*128 + q*8);
      f32x4 acc = {0.f,0.f,0.f,0.f};
      #pragma unroll
      for (int kf=0;kf<4;kf++)
        acc = __builtin_amdgcn_mfma_f32_16x16x32_bf16(a[kf], Brow[kf*4], acc, 0,0,0);
      #pragma unroll
      for (int g=0; g<4; g++)
        g24[(size_t)(mt*16 + q*4 + g)*128 + nt*16 + r] = acc[g];
    }
  }
}

// ---- K4d: beta = (sigmoid(nh@glu + b + g) @ w) per row, fused ----
__global__ __launch_bounds__(256) void k4d(const unsigned short* __restrict__ nh1,
    const unsigned short* __restrict__ nh2, const unsigned short* __restrict__ wT,
    const float* __restrict__ glu1_b, const float* __restrict__ glu3_b,
    const float* __restrict__ g24, const float* __restrict__ w2, const float* __restrict__ w4,
    float* __restrict__ beta1, float* __restrict__ beta2){
  __shared__ float sb[4][2][16];
  int mt = blockIdx.x;
  int wv = threadIdx.x>>6, lane = threadIdx.x&63;
  int r = lane&15, q = lane>>4;
  int bidx[4];
  #pragma unroll
  for (int g=0; g<4; g++) bidx[g] = (mt*16 + q*4 + g)/10;
  const bf16x8* A1 = (const bf16x8*)(nh1 + (size_t)(mt*16+r)*128 + q*8);
  const bf16x8* A2 = (const bf16x8*)(nh2 + (size_t)(mt*16+r)*128 + q*8);
  bf16x8 a1[4], a2[4];
  #pragma unroll
  for (int kf=0;kf<4;kf++){ a1[kf] = A1[kf*4]; a2[kf] = A2[kf*4]; }
  float accum0[4] = {0.f,0.f,0.f,0.f};
  float accum1[4] = {0.f,0.f,0.f,0.f};
  #pragma unroll
  for (int i=0;i<2;i++){
    int nt = wv + 4*i;
    int col = nt*16 + r;
    {
      const bf16x8* Brow = (const bf16x8*)(wT + G1T + (size_t)col*128 + q*8);
      f32x4 acc = {0.f,0.f,0.f,0.f};
      #pragma unroll
      for (int kf=0;kf<4;kf++)
        acc = __builtin_amdgcn_mfma_f32_16x16x32_bf16(a1[kf], Brow[kf*4], acc, 0,0,0);
      float gb = glu1_b[col], wc = w2[col];
      #pragma unroll
      for (int g=0; g<4; g++){
        float S = acc[g] + gb + g24[(size_t)bidx[g]*128 + col];
        accum0[g] += sigm(S)*wc;
      }
    }
    {
      const bf16x8* Brow = (const bf16x8*)(wT + G3T + (size_t)col*128 + q*8);
      f32x4 acc = {0.f,0.f,0.f,0.f};
      #pragma unroll
      for (int kf=0;kf<4;kf++)
        acc = __builtin_amdgcn_mfma_f32_16x16x32_bf16(a2[kf], Brow[kf*4], acc, 0,0,0);
      float gb = glu3_b[col], wc = w4[col];
      #pragma unroll
      for (int g=0; g<4; g++){
        float S = acc[g] + gb + g24[(size_t)(512 + bidx[g])*128 + col];
        accum1[g] += sigm(S)*wc;
      }
    }
  }
  #pragma unroll
  for (int g=0; g<4; g++){
    float v0 = accum0[g], v1 = accum1[g];
    v0 += __shfl_xor(v0,1,64); v0 += __shfl_xor(v0,2,64); v0 += __shfl_xor(v0,4,64); v0 += __shfl_xor(v0,8,64);
    v1 += __shfl_xor(v1,1,64); v1 += __shfl_xor(v1,2,64); v1 += __shfl_xor(v1,4,64); v1 += __shfl_xor(v1,8,64);
    accum0[g] = v0; accum1[g] = v1;
  }
  if (r == 0){
    #pragma unroll
    for (int g=0; g<4; g++){
      sb[wv][0][q*4+g] = accum0[g];
      sb[wv][1][q*4+g] = accum1[g];
    }
  }
  __syncthreads();
  if (threadIdx.x < 32){
    int m = threadIdx.x>>4, row = threadIdx.x&15;
    float s = sb[0][m][row]+sb[1][m][row]+sb[2][m][row]+sb[3][m][row];
    if (m) beta2[mt*16+row] = s; else beta1[mt*16+row] = s;
  }
}

// ---- K4e: sess vectors, alpha, seq_emb -> bf16 in MFMA A-fragment-linear layout ----
__global__ __launch_bounds__(128) void k4e(const int* __restrict__ mask,
    const float* __restrict__ beta1, const float* __restrict__ beta2,
    const float* __restrict__ ie, const float* __restrict__ ue,
    const float* __restrict__ wc_w, const float* __restrict__ wc_b,
    unsigned short* __restrict__ semb){
  __shared__ float red[2];
  __shared__ float alphaS;
  int b = blockIdx.x, t = threadIdx.x;
  float sv = 0.f, su = 0.f;
  #pragma unroll
  for (int l=0;l<L;l++){
    float m = (float)mask[b*L+l];
    float b1 = beta1[b*L+l]*m, b2 = beta2[b*L+l]*m;
    float v = ie[(size_t)(b*L+l)*D+t];
    sv += b1*v; su += b2*v;
  }
  float partial = sv*wc_w[t] + su*wc_w[D+t];
  #pragma unroll
  for (int off=32; off; off>>=1) partial += __shfl_down(partial, off, 64);
  if ((t&63)==0) red[t>>6] = partial;
  __syncthreads();
  if (t==0) alphaS = sigm(red[0]+red[1]+wc_b[0]);
  __syncthreads();
  float al = alphaS;
  float val = ue[(size_t)b*D+t] + al*sv + (1.f-al)*su;
  int mt = b>>4, r = b&15;
  int kf = t>>5, q = (t>>3)&3, j = t&7;
  semb[(size_t)((mt*4+kf)*64 + q*16 + r)*8 + j] = f2bf(val);
}

// ---- K5: scores = seq_emb(512x128) @ v2e[1:]^T, MFMA bf16, f32 out (nontemporal) ----
__global__ __launch_bounds__(256) void k_scores(const unsigned short* __restrict__ Afrag,
                                                const float* __restrict__ v2e,
                                                float* __restrict__ out){
  int tid = threadIdx.x;
  int wv = tid >> 6, lane = tid & 63;
  int q = lane >> 4, r = lane & 15;
  int ntile = blockIdx.x*4 + wv;
  int n = ntile*16 + r;
  bool valid = (ntile < NTILES) && (n < NOUT);
  int brow = valid ? (1 + n) : 0;
  const float4* Bf = (const float4*)(v2e + (size_t)brow*D + q*8);
  bf16x8 b[4];
  #pragma unroll
  for (int kf=0; kf<4; kf++){
    float4 lo = Bf[kf*8];      // cols kf*32 + q*8 + 0..3
    float4 hi = Bf[kf*8 + 1];  // cols kf*32 + q*8 + 4..7
    b[kf][0] = (short)f2bf(lo.x); b[kf][1] = (short)f2bf(lo.y);
    b[kf][2] = (short)f2bf(lo.z); b[kf][3] = (short)f2bf(lo.w);
    b[kf][4] = (short)f2bf(hi.x); b[kf][5] = (short)f2bf(hi.y);
    b[kf][6] = (short)f2bf(hi.z); b[kf][7] = (short)f2bf(hi.w);
  }
  const bf16x8* Af = (const bf16x8*)Afrag;
  int mbase = blockIdx.y*16;
  for (int u=0; u<8; ++u){
    int mt0 = mbase + u*2;
    bf16x8 a0[4], a1[4];
    #pragma unroll
    for (int kf=0;kf<4;kf++) a0[kf] = Af[(size_t)(mt0*4+kf)*64 + lane];
    #pragma unroll
    for (int kf=0;kf<4;kf++) a1[kf] = Af[(size_t)((mt0+1)*4+kf)*64 + lane];
    f32x4 acc0 = {0.f,0.f,0.f,0.f};
    f32x4 acc1 = {0.f,0.f,0.f,0.f};
    #pragma unroll
    for (int kf=0;kf<4;kf++)
      acc0 = __builtin_amdgcn_mfma_f32_16x16x32_bf16(a0[kf], b[kf], acc0, 0,0,0);
    #pragma unroll
    for (int kf=0;kf<4;kf++)
      acc1 = __builtin_amdgcn_mfma_f32_16x16x32_bf16(a1[kf], b[kf], acc1, 0,0,0);
    if (valid){
      size_t base0 = (size_t)(mt0*16 + q*4)*NOUT + n;
      __builtin_nontemporal_store(acc0[0], &out[base0]);
      __builtin_nontemporal_store(acc0[1], &out[base0 +   NOUT]);
      __builtin_nontemporal_store(acc0[2], &out[base0 + 2*NOUT]);
      __builtin_nontemporal_store(acc0[3], &out[base0 + 3*NOUT]);
      size_t base1 = base0 + (size_t)16*NOUT;
      __builtin_nontemporal_store(acc1[0], &out[base1]);
      __builtin_nontemporal_store(acc1[1], &out[base1 +   NOUT]);
      __builtin_nontemporal_store(acc1[2], &out[base1 + 2*NOUT]);
      __builtin_nontemporal_store(acc1[3], &out[base1 + 3*NOUT]);
    }
  }
}

extern "C" void kernel_launch(void* const* d_in, const int* in_sizes, int n_in,
                              void* d_out, int out_size, void* d_ws, size_t ws_size,
                              hipStream_t stream) {
  const int* user     = (const int*)d_in[0];
  const int* seq      = (const int*)d_in[1];
  const int* maskp    = (const int*)d_in[2];
  const int* pos_idx  = (const int*)d_in[4];
  const int* esrc     = (const int*)d_in[5];
  const int* edst     = (const int*)d_in[6];
  const int* item_num = (const int*)d_in[7];
  const float* v2e    = (const float*)d_in[8];
  const float* pos_w  = (const float*)d_in[9];
  const float* Wself  = (const float*)d_in[10];
  const float* Wneigh = (const float*)d_in[11];
  const float* bsage  = (const float*)d_in[12];
  const float* w1     = (const float*)d_in[13];
  const float* w2     = (const float*)d_in[14];
  const float* glu1_w = (const float*)d_in[15];
  const float* glu1_b = (const float*)d_in[16];
  const float* glu2_w = (const float*)d_in[17];
  const float* w3     = (const float*)d_in[18];
  const float* w4     = (const float*)d_in[19];
  const float* glu3_w = (const float*)d_in[20];
  const float* glu3_b = (const float*)d_in[21];
  const float* glu4_w = (const float*)d_in[22];
  const float* wc_w   = (const float*)d_in[23];
  const float* wc_b   = (const float*)d_in[24];
  float* out = (float*)d_out;

  // ---- small scratch in d_ws ----
  char* ws = (char*)d_ws;
  size_t off = 0;
  auto take = [&](size_t n){ size_t o = off; off += (n + 255) & ~(size_t)255; return o; };
  size_t o_cnt    = take(16);
  size_t o_cursor = take((size_t)MAXS*4);
  size_t o_invmap = take((size_t)MAXS*4);
  size_t o_beta1  = take((size_t)BS*L*4);
  size_t o_beta2  = take((size_t)BS*L*4);
  size_t o_semb   = take((size_t)BS*D*2);
  int* counters = (int*)(ws + o_cnt);
  int* cursor   = (int*)(ws + o_cursor);
  int* invmap   = (int*)(ws + o_invmap);
  float* beta1  = (float*)(ws + o_beta1);
  float* beta2  = (float*)(ws + o_beta2);
  unsigned short* semb = (unsigned short*)(ws + o_semb);

  // ---- big scratch in d_out tail (fully consumed before k_scores writes) ----
  char* outb = (char*)d_out;
  size_t to = 84000000;
  auto takeT = [&](size_t n){ size_t o = to; to += (n + 255) & ~(size_t)255; return o; };
  int*            map    = (int*)(outb + takeT((size_t)N_NODES*4));
  int*            bucket = (int*)(outb + takeT((size_t)MAXS*CAP*4));
  float*          neigh  = (float*)(outb + takeT((size_t)MAXS*D*4));
  float*          h1c    = (float*)(outb + takeT((size_t)MAXS*D*4));
  unsigned short* Xcat   = (unsigned short*)(outb + takeT((size_t)BS*L*256*2));
  unsigned short* nh1    = (unsigned short*)(outb + takeT((size_t)BS*L*D*2));
  unsigned short* nh2    = (unsigned short*)(outb + takeT((size_t)BS*L*D*2));
  unsigned short* AU     = (unsigned short*)(outb + takeT((size_t)2*BS*D*2));
  float*          g24    = (float*)(outb + takeT((size_t)2*BS*D*4));
  float*          ie     = (float*)(outb + takeT((size_t)BS*L*D*4));
  float*          ue     = (float*)(outb + takeT((size_t)BS*D*4));
  unsigned short* wT     = (unsigned short*)(outb + takeT((size_t)WT_ELEMS*2));

  k_prep<<<512, 256, 0, stream>>>(w1, w3, glu1_w, glu2_w, glu3_w, glu4_w, wT,
                                  map, cursor, counters);
  k_markcompact<<<(MAXS + 255)/256, 256, 0, stream>>>(seq, user, item_num, map, invmap, counters);
  k_scatter<<<512, 256, 0, stream>>>(esrc, edst, map, cursor, bucket);
  k_neigh<<<MAXS, D, 0, stream>>>(v2e, bucket, cursor, counters, neigh);
  k_h1<<<(MAXS + SL8 - 1)/SL8, D, 0, stream>>>(v2e, neigh, invmap, counters, Wself, Wneigh, bsage, h1c);
  k4a<<<BS, D, 0, stream>>>(user, seq, maskp, pos_idx, item_num, map, h1c, v2e, pos_w,
                            ie, ue, Xcat, AU);
  k4bc<<<384, 256, 0, stream>>>(Xcat, AU, wT, nh1, nh2, g24);
  k4d<<<BS*L/16, 256, 0, stream>>>(nh1, nh2, wT, glu1_b, glu3_b, g24, w2, w4, beta1, beta2);
  k4e<<<BS, D, 0, stream>>>(maskp, beta1, beta2, ie, ue, wc_w, wc_b, semb);
  k_scores<<<dim3(782, 2), 256, 0, stream>>>(semb, v2e, out);
}

// Round 3
// 303.954 us; speedup vs baseline: 1.1328x; 1.1328x over previous
//
#include <hip/hip_runtime.h>
#include <hip/hip_bf16.h>

#define N_NODES 50000
#define N_EDGES 600000
#define D 128
#define BS 512
#define L 10
#define MAXS (BS*L + BS)   // 5632 max needed slots
#define NOUT 49999
#define NTILES 3125        // ceil(49999/16)
#define CAP 64             // per-slot edge bucket capacity (deg ~ Poisson(12))

// wT element offsets (bf16, (n,k) layout)
#define W1T 0        // 128 x 256
#define W3T 32768    // 128 x 128
#define G1T 49152
#define G2T 65536
#define G3T 81920
#define G4T 98304
#define WT_ELEMS 114688

typedef __attribute__((ext_vector_type(8))) short bf16x8;
typedef __attribute__((ext_vector_type(4))) float f32x4;

__device__ __forceinline__ unsigned short f2bf(float f){
  union { float f; unsigned int i; } v; v.f = f;
  unsigned int i = v.i;
  return (unsigned short)((i + 0x7fffu + ((i >> 16) & 1u)) >> 16);
}
__device__ __forceinline__ float sigm(float x){ return 1.f/(1.f+__expf(-x)); }
__device__ __forceinline__ float tanh_f(float x){
  x = fminf(fmaxf(x, -15.f), 15.f);
  float e = __expf(2.f*x);
  return (e-1.f)/(e+1.f);
}

// ---- K_prep: transpose+cvt weights to bf16 (n,k) layout; blocks 448..511 zero scratch ----
__global__ __launch_bounds__(256) void k_prep(const float* __restrict__ w1,
    const float* __restrict__ w3, const float* __restrict__ g1,
    const float* __restrict__ g2, const float* __restrict__ g3,
    const float* __restrict__ g4, unsigned short* __restrict__ wT,
    int* __restrict__ map, int* __restrict__ cursor, int* __restrict__ counters){
  int bid = blockIdx.x, tid = threadIdx.x;
  if (bid < 128){
    int e = bid*256 + tid;
    int k = e >> 7, n = e & 127;
    wT[W1T + n*256 + k] = f2bf(w1[e]);
  } else if (bid < 448){
    int mm = (bid - 128) >> 6;
    int e = ((bid - 128) & 63)*256 + tid;
    int k = e >> 7, n = e & 127;
    const float* src = (mm==0)? w3 : (mm==1)? g1 : (mm==2)? g2 : (mm==3)? g3 : g4;
    int dst = (mm==0)? W3T : (mm==1)? G1T : (mm==2)? G2T : (mm==3)? G3T : G4T;
    wT[dst + n*128 + k] = f2bf(src[e]);
  } else {
    // zero map (N_NODES), cursor (MAXS), counters (4)
    const int TOT = N_NODES + MAXS + 4;
    for (int idx = (bid-448)*256 + tid; idx < TOT; idx += 64*256){
      if (idx < N_NODES) map[idx] = 0;
      else if (idx < N_NODES + MAXS) cursor[idx - N_NODES] = 0;
      else counters[idx - N_NODES - MAXS] = 0;
    }
  }
}

// ---- K1: mark + compact fused; CAS winner allocates the slot ----
__global__ void k_markcompact(const int* __restrict__ seq, const int* __restrict__ user,
                              const int* __restrict__ item_num, int* __restrict__ map,
                              int* __restrict__ invmap, int* __restrict__ counters){
  int i = blockIdx.x*256 + threadIdx.x;
  int node = -1;
  if (i < BS*L) node = seq[i];
  else if (i < BS*L + BS) node = user[i - BS*L] + item_num[0];
  if (node >= 0){
    if (atomicCAS(&map[node], 0, 1) == 0){
      int s = atomicAdd(&counters[0], 1);
      invmap[s] = node;
      map[node] = s + 2;
    }
  }
}

// ---- K2: single-pass scatter into fixed-capacity buckets; cursor = degree ----
__global__ void k_scatter(const int* __restrict__ esrc, const int* __restrict__ edst,
                          const int* __restrict__ map, int* __restrict__ cursor,
                          int* __restrict__ bucket){
  for (int e = blockIdx.x*blockDim.x + threadIdx.x; e < N_EDGES; e += gridDim.x*blockDim.x){
    int mv = map[edst[e]];
    if (mv >= 2){
      int slot = mv - 2;
      int pos = atomicAdd(&cursor[slot], 1);
      if (pos < CAP) bucket[slot*CAP + pos] = esrc[e];
    }
  }
}

// ---- K_nh: fused neigh-gather + h1 GEMM (8 slots/block, neigh lives in LDS) ----
// Gather loop is j-major over 8 unrolled slot accumulators -> 8 independent
// load chains per thread (preserves the MLP the separate 1-slot/block kernel had).
#define SL8 8
__global__ __launch_bounds__(128) void k_nh(const float* __restrict__ v2e,
                     const int* __restrict__ bucket, const int* __restrict__ cursor,
                     const int* __restrict__ invmap, const int* __restrict__ counters,
                     const float* __restrict__ Wself, const float* __restrict__ Wneigh,
                     const float* __restrict__ bsage, float* __restrict__ h1c){
  __shared__ float vv[SL8][D];
  __shared__ float nn[SL8][D];
  int t = threadIdx.x;
  int nslots = counters[0];
  int sb = blockIdx.x*SL8;
  float acc[SL8];
  int cnt[SL8], deg[SL8];
  int mx = 0;
  #pragma unroll
  for (int i=0;i<SL8;i++){
    int s = sb+i;
    bool ok = (s < nslots);
    deg[i] = ok ? cursor[s] : 0;
    cnt[i] = min(deg[i], CAP);
    mx = max(mx, cnt[i]);
    acc[i] = 0.f;
    vv[i][t] = ok ? v2e[(size_t)invmap[s]*D + t] : 0.f;
  }
  for (int j=0;j<mx;j++){
    #pragma unroll
    for (int i=0;i<SL8;i++){
      if (j < cnt[i]){
        int src = bucket[(sb+i)*CAP + j];
        acc[i] += v2e[(size_t)src*D + t];
      }
    }
  }
  #pragma unroll
  for (int i=0;i<SL8;i++) nn[i][t] = acc[i] / fmaxf((float)deg[i], 1.0f);
  __syncthreads();
  float bias = bsage[t];
  float hacc[SL8];
  #pragma unroll
  for (int i=0;i<SL8;i++) hacc[i] = bias;
  for (int k=0;k<D;k++){
    float ws = Wself[k*D + t];
    float wn = Wneigh[k*D + t];
    #pragma unroll
    for (int i=0;i<SL8;i++) hacc[i] += vv[i][k]*ws + nn[i][k]*wn;
  }
  for (int i=0;i<SL8;i++){
    int s = sb+i;
    if (s < nslots) h1c[(size_t)s*D + t] = fmaxf(hacc[i], 0.f);
  }
}

// ---- K4a: gather ie/pe/ue/avg; build bf16 A-matrices ----
__global__ __launch_bounds__(128) void k4a(const int* __restrict__ user, const int* __restrict__ seq,
    const int* __restrict__ mask, const int* __restrict__ pos_idx, const int* __restrict__ item_num,
    const int* __restrict__ map, const float* __restrict__ h1c, const float* __restrict__ v2e,
    const float* __restrict__ pos_w, float* __restrict__ ie, float* __restrict__ ue,
    unsigned short* __restrict__ Xcat, unsigned short* __restrict__ AU){
  int b = blockIdx.x, t = threadIdx.x;
  float av = 0.f, msum = 0.f;
  for (int l=0;l<L;l++){
    int node = seq[b*L+l];
    int slot = map[node]-2;
    float v = 0.5f*(h1c[(size_t)slot*D+t] + v2e[(size_t)node*D+t]);
    ie[(size_t)(b*L+l)*D+t] = v;
    Xcat[(size_t)(b*L+l)*256 + 128 + t] = f2bf(v);
    int p = pos_idx[b*L+l];
    Xcat[(size_t)(b*L+l)*256 + t] = f2bf(pos_w[(size_t)p*D+t]);
    float m = (float)mask[b*L+l];
    av += v*m; msum += m;
  }
  AU[(size_t)b*D+t] = f2bf(av/msum);
  int unode = user[b]+item_num[0];
  int uslot = map[unode]-2;
  float uv = 0.5f*(h1c[(size_t)uslot*D+t] + v2e[(size_t)unode*D+t]);
  ue[(size_t)b*D+t] = uv;
  AU[(size_t)(512+b)*D+t] = f2bf(uv);
}

// ---- K4bc: blocks 0..319: nh1/nh2 GEMMs. blocks 320..383: g24 GEMM. ----
__global__ __launch_bounds__(256) void k4bc(const unsigned short* __restrict__ Xcat,
    const unsigned short* __restrict__ AU, const unsigned short* __restrict__ wT,
    unsigned short* __restrict__ nh1, unsigned short* __restrict__ nh2,
    float* __restrict__ g24){
  int wv = threadIdx.x>>6, lane = threadIdx.x&63;
  int r = lane&15, q = lane>>4;
  if (blockIdx.x < 320){
    int mt = blockIdx.x;
    const bf16x8* Arow = (const bf16x8*)(Xcat + (size_t)(mt*16+r)*256 + q*8);
    bf16x8 a[8];
    #pragma unroll
    for (int kf=0;kf<8;kf++) a[kf] = Arow[kf*4];
    #pragma unroll
    for (int i=0;i<2;i++){   // nh1, K=256
      int nt = wv + 4*i;
      const bf16x8* Brow = (const bf16x8*)(wT + W1T + (size_t)(nt*16+r)*256 + q*8);
      f32x4 acc = {0.f,0.f,0.f,0.f};
      #pragma unroll
      for (int kf=0;kf<8;kf++)
        acc = __builtin_amdgcn_mfma_f32_16x16x32_bf16(a[kf], Brow[kf*4], acc, 0,0,0);
      #pragma unroll
      for (int g=0; g<4; g++)
        nh1[(size_t)(mt*16 + q*4 + g)*128 + nt*16 + r] = f2bf(tanh_f(acc[g]));
    }
    #pragma unroll
    for (int i=0;i<2;i++){   // nh2, K=128 (ie = Xcat cols 128..255 -> a[4..7])
      int nt = wv + 4*i;
      const bf16x8* Brow = (const bf16x8*)(wT + W3T + (size_t)(nt*16+r)*128 + q*8);
      f32x4 acc = {0.f,0.f,0.f,0.f};
      #pragma unroll
      for (int kf=0;kf<4;kf++)
        acc = __builtin_amdgcn_mfma_f32_16x16x32_bf16(a[4+kf], Brow[kf*4], acc, 0,0,0);
      #pragma unroll
      for (int g=0; g<4; g++)
        nh2[(size_t)(mt*16 + q*4 + g)*128 + nt*16 + r] = f2bf(tanh_f(acc[g]));
    }
  } else {
    int mt = blockIdx.x - 320;  // 0..63
    const unsigned short* Bbase = wT + ((mt*16 >= 512) ? G4T : G2T);
    const bf16x8* Arow = (const bf16x8*)(AU + (size_t)(mt*16+r)*128 + q*8);
    bf16x8 a[4];
    #pragma unroll
    for (int kf=0;kf<4;kf++) a[kf] = Arow[kf*4];
    #pragma unroll
    for (int i=0;i<2;i++){
      int nt = wv + 4*i;
      const bf16x8* Brow = (const bf16x8*)(Bbase + (size_t)(nt*16+r)*128 + q*8);
      f32x4 acc = {0.f,0.f,0.f,0.f};
      #pragma unroll
      for (int kf=0;kf<4;kf++)
        acc = __builtin_amdgcn_mfma_f32_16x16x32_bf16(a[kf], Brow[kf*4], acc, 0,0,0);
      #pragma unroll
      for (int g=0; g<4; g++)
        g24[(size_t)(mt*16 + q*4 + g)*128 + nt*16 + r] = acc[g];
    }
  }
}

// ---- K4d: beta = (sigmoid(nh@glu + b + g) @ w) per row, fused ----
__global__ __launch_bounds__(256) void k4d(const unsigned short* __restrict__ nh1,
    const unsigned short* __restrict__ nh2, const unsigned short* __restrict__ wT,
    const float* __restrict__ glu1_b, const float* __restrict__ glu3_b,
    const float* __restrict__ g24, const float* __restrict__ w2, const float* __restrict__ w4,
    float* __restrict__ beta1, float* __restrict__ beta2){
  __shared__ float sb[4][2][16];
  int mt = blockIdx.x;
  int wv = threadIdx.x>>6, lane = threadIdx.x&63;
  int r = lane&15, q = lane>>4;
  int bidx[4];
  #pragma unroll
  for (int g=0; g<4; g++) bidx[g] = (mt*16 + q*4 + g)/10;
  const bf16x8* A1 = (const bf16x8*)(nh1 + (size_t)(mt*16+r)*128 + q*8);
  const bf16x8* A2 = (const bf16x8*)(nh2 + (size_t)(mt*16+r)*128 + q*8);
  bf16x8 a1[4], a2[4];
  #pragma unroll
  for (int kf=0;kf<4;kf++){ a1[kf] = A1[kf*4]; a2[kf] = A2[kf*4]; }
  float accum0[4] = {0.f,0.f,0.f,0.f};
  float accum1[4] = {0.f,0.f,0.f,0.f};
  #pragma unroll
  for (int i=0;i<2;i++){
    int nt = wv + 4*i;
    int col = nt*16 + r;
    {
      const bf16x8* Brow = (const bf16x8*)(wT + G1T + (size_t)col*128 + q*8);
      f32x4 acc = {0.f,0.f,0.f,0.f};
      #pragma unroll
      for (int kf=0;kf<4;kf++)
        acc = __builtin_amdgcn_mfma_f32_16x16x32_bf16(a1[kf], Brow[kf*4], acc, 0,0,0);
      float gb = glu1_b[col], wc = w2[col];
      #pragma unroll
      for (int g=0; g<4; g++){
        float S = acc[g] + gb + g24[(size_t)bidx[g]*128 + col];
        accum0[g] += sigm(S)*wc;
      }
    }
    {
      const bf16x8* Brow = (const bf16x8*)(wT + G3T + (size_t)col*128 + q*8);
      f32x4 acc = {0.f,0.f,0.f,0.f};
      #pragma unroll
      for (int kf=0;kf<4;kf++)
        acc = __builtin_amdgcn_mfma_f32_16x16x32_bf16(a2[kf], Brow[kf*4], acc, 0,0,0);
      float gb = glu3_b[col], wc = w4[col];
      #pragma unroll
      for (int g=0; g<4; g++){
        float S = acc[g] + gb + g24[(size_t)(512 + bidx[g])*128 + col];
        accum1[g] += sigm(S)*wc;
      }
    }
  }
  #pragma unroll
  for (int g=0; g<4; g++){
    float v0 = accum0[g], v1 = accum1[g];
    v0 += __shfl_xor(v0,1,64); v0 += __shfl_xor(v0,2,64); v0 += __shfl_xor(v0,4,64); v0 += __shfl_xor(v0,8,64);
    v1 += __shfl_xor(v1,1,64); v1 += __shfl_xor(v1,2,64); v1 += __shfl_xor(v1,4,64); v1 += __shfl_xor(v1,8,64);
    accum0[g] = v0; accum1[g] = v1;
  }
  if (r == 0){
    #pragma unroll
    for (int g=0; g<4; g++){
      sb[wv][0][q*4+g] = accum0[g];
      sb[wv][1][q*4+g] = accum1[g];
    }
  }
  __syncthreads();
  if (threadIdx.x < 32){
    int m = threadIdx.x>>4, row = threadIdx.x&15;
    float s = sb[0][m][row]+sb[1][m][row]+sb[2][m][row]+sb[3][m][row];
    if (m) beta2[mt*16+row] = s; else beta1[mt*16+row] = s;
  }
}

// ---- K4e: sess vectors, alpha, seq_emb -> bf16 in MFMA A-fragment-linear layout ----
__global__ __launch_bounds__(128) void k4e(const int* __restrict__ mask,
    const float* __restrict__ beta1, const float* __restrict__ beta2,
    const float* __restrict__ ie, const float* __restrict__ ue,
    const float* __restrict__ wc_w, const float* __restrict__ wc_b,
    unsigned short* __restrict__ semb){
  __shared__ float red[2];
  __shared__ float alphaS;
  int b = blockIdx.x, t = threadIdx.x;
  float sv = 0.f, su = 0.f;
  #pragma unroll
  for (int l=0;l<L;l++){
    float m = (float)mask[b*L+l];
    float b1 = beta1[b*L+l]*m, b2 = beta2[b*L+l]*m;
    float v = ie[(size_t)(b*L+l)*D+t];
    sv += b1*v; su += b2*v;
  }
  float partial = sv*wc_w[t] + su*wc_w[D+t];
  #pragma unroll
  for (int off=32; off; off>>=1) partial += __shfl_down(partial, off, 64);
  if ((t&63)==0) red[t>>6] = partial;
  __syncthreads();
  if (t==0) alphaS = sigm(red[0]+red[1]+wc_b[0]);
  __syncthreads();
  float al = alphaS;
  float val = ue[(size_t)b*D+t] + al*sv + (1.f-al)*su;
  int mt = b>>4, r = b&15;
  int kf = t>>5, q = (t>>3)&3, j = t&7;
  semb[(size_t)((mt*4+kf)*64 + q*16 + r)*8 + j] = f2bf(val);
}

// ---- K5: scores = seq_emb(512x128) @ v2e[1:]^T, MFMA bf16, f32 out ----
// grid (782, 2): each block = 4 n-tiles (64 cols) x 16 m-tiles (256 rows).
// NORMAL stores (L2 merges partial lines; NT stores caused 1.45x write amplification).
__global__ __launch_bounds__(256) void k_scores(const unsigned short* __restrict__ Afrag,
                                                const float* __restrict__ v2e,
                                                float* __restrict__ out){
  int tid = threadIdx.x;
  int wv = tid >> 6, lane = tid & 63;
  int q = lane >> 4, r = lane & 15;
  int ntile = blockIdx.x*4 + wv;
  int n = ntile*16 + r;
  bool valid = (ntile < NTILES) && (n < NOUT);
  int brow = valid ? (1 + n) : 0;
  const float4* Bf = (const float4*)(v2e + (size_t)brow*D + q*8);
  bf16x8 b[4];
  #pragma unroll
  for (int kf=0; kf<4; kf++){
    float4 lo = Bf[kf*8];      // cols kf*32 + q*8 + 0..3
    float4 hi = Bf[kf*8 + 1];  // cols kf*32 + q*8 + 4..7
    b[kf][0] = (short)f2bf(lo.x); b[kf][1] = (short)f2bf(lo.y);
    b[kf][2] = (short)f2bf(lo.z); b[kf][3] = (short)f2bf(lo.w);
    b[kf][4] = (short)f2bf(hi.x); b[kf][5] = (short)f2bf(hi.y);
    b[kf][6] = (short)f2bf(hi.z); b[kf][7] = (short)f2bf(hi.w);
  }
  const bf16x8* Af = (const bf16x8*)Afrag;
  int mbase = blockIdx.y*16;
  for (int u=0; u<8; ++u){
    int mt0 = mbase + u*2;
    bf16x8 a0[4], a1[4];
    #pragma unroll
    for (int kf=0;kf<4;kf++) a0[kf] = Af[(size_t)(mt0*4+kf)*64 + lane];
    #pragma unroll
    for (int kf=0;kf<4;kf++) a1[kf] = Af[(size_t)((mt0+1)*4+kf)*64 + lane];
    f32x4 acc0 = {0.f,0.f,0.f,0.f};
    f32x4 acc1 = {0.f,0.f,0.f,0.f};
    #pragma unroll
    for (int kf=0;kf<4;kf++)
      acc0 = __builtin_amdgcn_mfma_f32_16x16x32_bf16(a0[kf], b[kf], acc0, 0,0,0);
    #pragma unroll
    for (int kf=0;kf<4;kf++)
      acc1 = __builtin_amdgcn_mfma_f32_16x16x32_bf16(a1[kf], b[kf], acc1, 0,0,0);
    if (valid){
      size_t base0 = (size_t)(mt0*16 + q*4)*NOUT + n;
      out[base0]          = acc0[0];
      out[base0 +   NOUT] = acc0[1];
      out[base0 + 2*NOUT] = acc0[2];
      out[base0 + 3*NOUT] = acc0[3];
      size_t base1 = base0 + (size_t)16*NOUT;
      out[base1]          = acc1[0];
      out[base1 +   NOUT] = acc1[1];
      out[base1 + 2*NOUT] = acc1[2];
      out[base1 + 3*NOUT] = acc1[3];
    }
  }
}

extern "C" void kernel_launch(void* const* d_in, const int* in_sizes, int n_in,
                              void* d_out, int out_size, void* d_ws, size_t ws_size,
                              hipStream_t stream) {
  const int* user     = (const int*)d_in[0];
  const int* seq      = (const int*)d_in[1];
  const int* maskp    = (const int*)d_in[2];
  const int* pos_idx  = (const int*)d_in[4];
  const int* esrc     = (const int*)d_in[5];
  const int* edst     = (const int*)d_in[6];
  const int* item_num = (const int*)d_in[7];
  const float* v2e    = (const float*)d_in[8];
  const float* pos_w  = (const float*)d_in[9];
  const float* Wself  = (const float*)d_in[10];
  const float* Wneigh = (const float*)d_in[11];
  const float* bsage  = (const float*)d_in[12];
  const float* w1     = (const float*)d_in[13];
  const float* w2     = (const float*)d_in[14];
  const float* glu1_w = (const float*)d_in[15];
  const float* glu1_b = (const float*)d_in[16];
  const float* glu2_w = (const float*)d_in[17];
  const float* w3     = (const float*)d_in[18];
  const float* w4     = (const float*)d_in[19];
  const float* glu3_w = (const float*)d_in[20];
  const float* glu3_b = (const float*)d_in[21];
  const float* glu4_w = (const float*)d_in[22];
  const float* wc_w   = (const float*)d_in[23];
  const float* wc_b   = (const float*)d_in[24];
  float* out = (float*)d_out;

  // ---- small scratch in d_ws ----
  char* ws = (char*)d_ws;
  size_t off = 0;
  auto take = [&](size_t n){ size_t o = off; off += (n + 255) & ~(size_t)255; return o; };
  size_t o_cnt    = take(16);
  size_t o_cursor = take((size_t)MAXS*4);
  size_t o_invmap = take((size_t)MAXS*4);
  size_t o_beta1  = take((size_t)BS*L*4);
  size_t o_beta2  = take((size_t)BS*L*4);
  size_t o_semb   = take((size_t)BS*D*2);
  int* counters = (int*)(ws + o_cnt);
  int* cursor   = (int*)(ws + o_cursor);
  int* invmap   = (int*)(ws + o_invmap);
  float* beta1  = (float*)(ws + o_beta1);
  float* beta2  = (float*)(ws + o_beta2);
  unsigned short* semb = (unsigned short*)(ws + o_semb);

  // ---- big scratch in d_out tail (fully consumed before k_scores writes) ----
  char* outb = (char*)d_out;
  size_t to = 84000000;
  auto takeT = [&](size_t n){ size_t o = to; to += (n + 255) & ~(size_t)255; return o; };
  int*            map    = (int*)(outb + takeT((size_t)N_NODES*4));
  int*            bucket = (int*)(outb + takeT((size_t)MAXS*CAP*4));
  float*          h1c    = (float*)(outb + takeT((size_t)MAXS*D*4));
  unsigned short* Xcat   = (unsigned short*)(outb + takeT((size_t)BS*L*256*2));
  unsigned short* nh1    = (unsigned short*)(outb + takeT((size_t)BS*L*D*2));
  unsigned short* nh2    = (unsigned short*)(outb + takeT((size_t)BS*L*D*2));
  unsigned short* AU     = (unsigned short*)(outb + takeT((size_t)2*BS*D*2));
  float*          g24    = (float*)(outb + takeT((size_t)2*BS*D*4));
  float*          ie     = (float*)(outb + takeT((size_t)BS*L*D*4));
  float*          ue     = (float*)(outb + takeT((size_t)BS*D*4));
  unsigned short* wT     = (unsigned short*)(outb + takeT((size_t)WT_ELEMS*2));

  k_prep<<<512, 256, 0, stream>>>(w1, w3, glu1_w, glu2_w, glu3_w, glu4_w, wT,
                                  map, cursor, counters);
  k_markcompact<<<(MAXS + 255)/256, 256, 0, stream>>>(seq, user, item_num, map, invmap, counters);
  k_scatter<<<512, 256, 0, stream>>>(esrc, edst, map, cursor, bucket);
  k_nh<<<(MAXS + SL8 - 1)/SL8, D, 0, stream>>>(v2e, bucket, cursor, invmap, counters,
                                               Wself, Wneigh, bsage, h1c);
  k4a<<<BS, D, 0, stream>>>(user, seq, maskp, pos_idx, item_num, map, h1c, v2e, pos_w,
                            ie, ue, Xcat, AU);
  k4bc<<<384, 256, 0, stream>>>(Xcat, AU, wT, nh1, nh2, g24);
  k4d<<<BS*L/16, 256, 0, stream>>>(nh1, nh2, wT, glu1_b, glu3_b, g24, w2, w4, beta1, beta2);
  k4e<<<BS, D, 0, stream>>>(maskp, beta1, beta2, ie, ue, wc_w, wc_b, semb);
  k_scores<<<dim3(782, 2), 256, 0, stream>>>(semb, v2e, out);
}

// Round 4
// 289.910 us; speedup vs baseline: 1.1877x; 1.0484x over previous
//
#include <hip/hip_runtime.h>
#include <hip/hip_bf16.h>

#define N_NODES 50000
#define N_EDGES 600000
#define D 128
#define BS 512
#define L 10
#define MAXS (BS*L + BS)   // 5632 max needed slots
#define NOUT 49999
#define NTILES 3125        // ceil(49999/16)
#define CAP 64             // per-slot edge bucket capacity (deg ~ Poisson(12))

// wT element offsets (bf16, (n,k) layout)
#define W1T 0        // 128 x 256
#define W3T 32768    // 128 x 128
#define G1T 49152
#define G2T 65536
#define G3T 81920
#define G4T 98304
#define WT_ELEMS 114688

typedef __attribute__((ext_vector_type(8))) short bf16x8;
typedef __attribute__((ext_vector_type(4))) float f32x4;

__device__ __forceinline__ unsigned short f2bf(float f){
  union { float f; unsigned int i; } v; v.f = f;
  unsigned int i = v.i;
  return (unsigned short)((i + 0x7fffu + ((i >> 16) & 1u)) >> 16);
}
__device__ __forceinline__ float sigm(float x){ return 1.f/(1.f+__expf(-x)); }
__device__ __forceinline__ float tanh_f(float x){
  x = fminf(fmaxf(x, -15.f), 15.f);
  float e = __expf(2.f*x);
  return (e-1.f)/(e+1.f);
}

// ---- K_prep: transpose+cvt weights to bf16 (n,k) layout; blocks 448..511 zero scratch ----
__global__ __launch_bounds__(256) void k_prep(const float* __restrict__ w1,
    const float* __restrict__ w3, const float* __restrict__ g1,
    const float* __restrict__ g2, const float* __restrict__ g3,
    const float* __restrict__ g4, unsigned short* __restrict__ wT,
    int* __restrict__ map, int* __restrict__ cursor, int* __restrict__ counters){
  int bid = blockIdx.x, tid = threadIdx.x;
  if (bid < 128){
    int e = bid*256 + tid;
    int k = e >> 7, n = e & 127;
    wT[W1T + n*256 + k] = f2bf(w1[e]);
  } else if (bid < 448){
    int mm = (bid - 128) >> 6;
    int e = ((bid - 128) & 63)*256 + tid;
    int k = e >> 7, n = e & 127;
    const float* src = (mm==0)? w3 : (mm==1)? g1 : (mm==2)? g2 : (mm==3)? g3 : g4;
    int dst = (mm==0)? W3T : (mm==1)? G1T : (mm==2)? G2T : (mm==3)? G3T : G4T;
    wT[dst + n*128 + k] = f2bf(src[e]);
  } else {
    // zero map (N_NODES), cursor (MAXS), counters (4)
    const int TOT = N_NODES + MAXS + 4;
    for (int idx = (bid-448)*256 + tid; idx < TOT; idx += 64*256){
      if (idx < N_NODES) map[idx] = 0;
      else if (idx < N_NODES + MAXS) cursor[idx - N_NODES] = 0;
      else counters[idx - N_NODES - MAXS] = 0;
    }
  }
}

// ---- K1: mark + compact fused; CAS winner allocates the slot ----
__global__ void k_markcompact(const int* __restrict__ seq, const int* __restrict__ user,
                              const int* __restrict__ item_num, int* __restrict__ map,
                              int* __restrict__ invmap, int* __restrict__ counters){
  int i = blockIdx.x*256 + threadIdx.x;
  int node = -1;
  if (i < BS*L) node = seq[i];
  else if (i < BS*L + BS) node = user[i - BS*L] + item_num[0];
  if (node >= 0){
    if (atomicCAS(&map[node], 0, 1) == 0){
      int s = atomicAdd(&counters[0], 1);
      invmap[s] = node;
      map[node] = s + 2;
    }
  }
}

// ---- K2: single-pass scatter into fixed-capacity buckets; cursor = degree ----
__global__ void k_scatter(const int* __restrict__ esrc, const int* __restrict__ edst,
                          const int* __restrict__ map, int* __restrict__ cursor,
                          int* __restrict__ bucket){
  for (int e = blockIdx.x*blockDim.x + threadIdx.x; e < N_EDGES; e += gridDim.x*blockDim.x){
    int mv = map[edst[e]];
    if (mv >= 2){
      int slot = mv - 2;
      int pos = atomicAdd(&cursor[slot], 1);
      if (pos < CAP) bucket[slot*CAP + pos] = esrc[e];
    }
  }
}

// ---- K2d: per-slot gather-sum -> neigh = agg/max(deg,1) ----
// ONE slot per block: 5632 blocks x 2 waves = high TLP; the random 512B row
// gathers are latency-hidden by wave count (fused 8-slot version was 74us @ 12% occ).
__global__ void k_neigh(const float* __restrict__ v2e, const int* __restrict__ bucket,
                        const int* __restrict__ cursor, const int* __restrict__ counters,
                        float* __restrict__ neigh){
  int s = blockIdx.x; int t = threadIdx.x;
  if (s >= counters[0]) return;
  int deg = cursor[s];
  int cnt = min(deg, CAP);
  float acc = 0.f;
  for (int j=0;j<cnt;j++){
    int src = bucket[s*CAP + j];
    acc += v2e[(size_t)src*D + t];
  }
  neigh[(size_t)s*D + t] = acc / fmaxf((float)deg, 1.0f);
}

// ---- K3: h1 for needed slots only (8 slots/block) ----
#define SL8 8
__global__ __launch_bounds__(128) void k_h1(const float* __restrict__ v2e,
                     const float* __restrict__ neigh, const int* __restrict__ invmap,
                     const int* __restrict__ counters, const float* __restrict__ Wself,
                     const float* __restrict__ Wneigh, const float* __restrict__ bsage,
                     float* __restrict__ h1c){
  __shared__ float vv[SL8][D];
  __shared__ float nn[SL8][D];
  int t = threadIdx.x;
  int nslots = counters[0];
  int sb = blockIdx.x*SL8;
  for (int i=0;i<SL8;i++){
    int s = sb+i;
    if (s < nslots){
      int node = invmap[s];
      vv[i][t] = v2e[(size_t)node*D + t];
      nn[i][t] = neigh[(size_t)s*D + t];
    }
  }
  __syncthreads();
  float bias = bsage[t];
  float acc[SL8];
  #pragma unroll
  for (int i=0;i<SL8;i++) acc[i] = bias;
  for (int k=0;k<D;k++){
    float ws = Wself[k*D + t];
    float wn = Wneigh[k*D + t];
    #pragma unroll
    for (int i=0;i<SL8;i++) acc[i] += vv[i][k]*ws + nn[i][k]*wn;
  }
  for (int i=0;i<SL8;i++){
    int s = sb+i;
    if (s < nslots) h1c[(size_t)s*D + t] = fmaxf(acc[i], 0.f);
  }
}

// ---- K4a: gather ie/pe/ue/avg; build bf16 A-matrices ----
__global__ __launch_bounds__(128) void k4a(const int* __restrict__ user, const int* __restrict__ seq,
    const int* __restrict__ mask, const int* __restrict__ pos_idx, const int* __restrict__ item_num,
    const int* __restrict__ map, const float* __restrict__ h1c, const float* __restrict__ v2e,
    const float* __restrict__ pos_w, float* __restrict__ ie, float* __restrict__ ue,
    unsigned short* __restrict__ Xcat, unsigned short* __restrict__ AU){
  int b = blockIdx.x, t = threadIdx.x;
  float av = 0.f, msum = 0.f;
  for (int l=0;l<L;l++){
    int node = seq[b*L+l];
    int slot = map[node]-2;
    float v = 0.5f*(h1c[(size_t)slot*D+t] + v2e[(size_t)node*D+t]);
    ie[(size_t)(b*L+l)*D+t] = v;
    Xcat[(size_t)(b*L+l)*256 + 128 + t] = f2bf(v);
    int p = pos_idx[b*L+l];
    Xcat[(size_t)(b*L+l)*256 + t] = f2bf(pos_w[(size_t)p*D+t]);
    float m = (float)mask[b*L+l];
    av += v*m; msum += m;
  }
  AU[(size_t)b*D+t] = f2bf(av/msum);
  int unode = user[b]+item_num[0];
  int uslot = map[unode]-2;
  float uv = 0.5f*(h1c[(size_t)uslot*D+t] + v2e[(size_t)unode*D+t]);
  ue[(size_t)b*D+t] = uv;
  AU[(size_t)(512+b)*D+t] = f2bf(uv);
}

// ---- K4bc: blocks 0..319: nh1/nh2 GEMMs. blocks 320..383: g24 GEMM. ----
__global__ __launch_bounds__(256) void k4bc(const unsigned short* __restrict__ Xcat,
    const unsigned short* __restrict__ AU, const unsigned short* __restrict__ wT,
    unsigned short* __restrict__ nh1, unsigned short* __restrict__ nh2,
    float* __restrict__ g24){
  int wv = threadIdx.x>>6, lane = threadIdx.x&63;
  int r = lane&15, q = lane>>4;
  if (blockIdx.x < 320){
    int mt = blockIdx.x;
    const bf16x8* Arow = (const bf16x8*)(Xcat + (size_t)(mt*16+r)*256 + q*8);
    bf16x8 a[8];
    #pragma unroll
    for (int kf=0;kf<8;kf++) a[kf] = Arow[kf*4];
    #pragma unroll
    for (int i=0;i<2;i++){   // nh1, K=256
      int nt = wv + 4*i;
      const bf16x8* Brow = (const bf16x8*)(wT + W1T + (size_t)(nt*16+r)*256 + q*8);
      f32x4 acc = {0.f,0.f,0.f,0.f};
      #pragma unroll
      for (int kf=0;kf<8;kf++)
        acc = __builtin_amdgcn_mfma_f32_16x16x32_bf16(a[kf], Brow[kf*4], acc, 0,0,0);
      #pragma unroll
      for (int g=0; g<4; g++)
        nh1[(size_t)(mt*16 + q*4 + g)*128 + nt*16 + r] = f2bf(tanh_f(acc[g]));
    }
    #pragma unroll
    for (int i=0;i<2;i++){   // nh2, K=128 (ie = Xcat cols 128..255 -> a[4..7])
      int nt = wv + 4*i;
      const bf16x8* Brow = (const bf16x8*)(wT + W3T + (size_t)(nt*16+r)*128 + q*8);
      f32x4 acc = {0.f,0.f,0.f,0.f};
      #pragma unroll
      for (int kf=0;kf<4;kf++)
        acc = __builtin_amdgcn_mfma_f32_16x16x32_bf16(a[4+kf], Brow[kf*4], acc, 0,0,0);
      #pragma unroll
      for (int g=0; g<4; g++)
        nh2[(size_t)(mt*16 + q*4 + g)*128 + nt*16 + r] = f2bf(tanh_f(acc[g]));
    }
  } else {
    int mt = blockIdx.x - 320;  // 0..63
    const unsigned short* Bbase = wT + ((mt*16 >= 512) ? G4T : G2T);
    const bf16x8* Arow = (const bf16x8*)(AU + (size_t)(mt*16+r)*128 + q*8);
    bf16x8 a[4];
    #pragma unroll
    for (int kf=0;kf<4;kf++) a[kf] = Arow[kf*4];
    #pragma unroll
    for (int i=0;i<2;i++){
      int nt = wv + 4*i;
      const bf16x8* Brow = (const bf16x8*)(Bbase + (size_t)(nt*16+r)*128 + q*8);
      f32x4 acc = {0.f,0.f,0.f,0.f};
      #pragma unroll
      for (int kf=0;kf<4;kf++)
        acc = __builtin_amdgcn_mfma_f32_16x16x32_bf16(a[kf], Brow[kf*4], acc, 0,0,0);
      #pragma unroll
      for (int g=0; g<4; g++)
        g24[(size_t)(mt*16 + q*4 + g)*128 + nt*16 + r] = acc[g];
    }
  }
}

// ---- K4d: beta = (sigmoid(nh@glu + b + g) @ w) per row, fused ----
__global__ __launch_bounds__(256) void k4d(const unsigned short* __restrict__ nh1,
    const unsigned short* __restrict__ nh2, const unsigned short* __restrict__ wT,
    const float* __restrict__ glu1_b, const float* __restrict__ glu3_b,
    const float* __restrict__ g24, const float* __restrict__ w2, const float* __restrict__ w4,
    float* __restrict__ beta1, float* __restrict__ beta2){
  __shared__ float sb[4][2][16];
  int mt = blockIdx.x;
  int wv = threadIdx.x>>6, lane = threadIdx.x&63;
  int r = lane&15, q = lane>>4;
  int bidx[4];
  #pragma unroll
  for (int g=0; g<4; g++) bidx[g] = (mt*16 + q*4 + g)/10;
  const bf16x8* A1 = (const bf16x8*)(nh1 + (size_t)(mt*16+r)*128 + q*8);
  const bf16x8* A2 = (const bf16x8*)(nh2 + (size_t)(mt*16+r)*128 + q*8);
  bf16x8 a1[4], a2[4];
  #pragma unroll
  for (int kf=0;kf<4;kf++){ a1[kf] = A1[kf*4]; a2[kf] = A2[kf*4]; }
  float accum0[4] = {0.f,0.f,0.f,0.f};
  float accum1[4] = {0.f,0.f,0.f,0.f};
  #pragma unroll
  for (int i=0;i<2;i++){
    int nt = wv + 4*i;
    int col = nt*16 + r;
    {
      const bf16x8* Brow = (const bf16x8*)(wT + G1T + (size_t)col*128 + q*8);
      f32x4 acc = {0.f,0.f,0.f,0.f};
      #pragma unroll
      for (int kf=0;kf<4;kf++)
        acc = __builtin_amdgcn_mfma_f32_16x16x32_bf16(a1[kf], Brow[kf*4], acc, 0,0,0);
      float gb = glu1_b[col], wc = w2[col];
      #pragma unroll
      for (int g=0; g<4; g++){
        float S = acc[g] + gb + g24[(size_t)bidx[g]*128 + col];
        accum0[g] += sigm(S)*wc;
      }
    }
    {
      const bf16x8* Brow = (const bf16x8*)(wT + G3T + (size_t)col*128 + q*8);
      f32x4 acc = {0.f,0.f,0.f,0.f};
      #pragma unroll
      for (int kf=0;kf<4;kf++)
        acc = __builtin_amdgcn_mfma_f32_16x16x32_bf16(a2[kf], Brow[kf*4], acc, 0,0,0);
      float gb = glu3_b[col], wc = w4[col];
      #pragma unroll
      for (int g=0; g<4; g++){
        float S = acc[g] + gb + g24[(size_t)(512 + bidx[g])*128 + col];
        accum1[g] += sigm(S)*wc;
      }
    }
  }
  #pragma unroll
  for (int g=0; g<4; g++){
    float v0 = accum0[g], v1 = accum1[g];
    v0 += __shfl_xor(v0,1,64); v0 += __shfl_xor(v0,2,64); v0 += __shfl_xor(v0,4,64); v0 += __shfl_xor(v0,8,64);
    v1 += __shfl_xor(v1,1,64); v1 += __shfl_xor(v1,2,64); v1 += __shfl_xor(v1,4,64); v1 += __shfl_xor(v1,8,64);
    accum0[g] = v0; accum1[g] = v1;
  }
  if (r == 0){
    #pragma unroll
    for (int g=0; g<4; g++){
      sb[wv][0][q*4+g] = accum0[g];
      sb[wv][1][q*4+g] = accum1[g];
    }
  }
  __syncthreads();
  if (threadIdx.x < 32){
    int m = threadIdx.x>>4, row = threadIdx.x&15;
    float s = sb[0][m][row]+sb[1][m][row]+sb[2][m][row]+sb[3][m][row];
    if (m) beta2[mt*16+row] = s; else beta1[mt*16+row] = s;
  }
}

// ---- K4e: sess vectors, alpha, seq_emb -> bf16 in MFMA A-fragment-linear layout ----
__global__ __launch_bounds__(128) void k4e(const int* __restrict__ mask,
    const float* __restrict__ beta1, const float* __restrict__ beta2,
    const float* __restrict__ ie, const float* __restrict__ ue,
    const float* __restrict__ wc_w, const float* __restrict__ wc_b,
    unsigned short* __restrict__ semb){
  __shared__ float red[2];
  __shared__ float alphaS;
  int b = blockIdx.x, t = threadIdx.x;
  float sv = 0.f, su = 0.f;
  #pragma unroll
  for (int l=0;l<L;l++){
    float m = (float)mask[b*L+l];
    float b1 = beta1[b*L+l]*m, b2 = beta2[b*L+l]*m;
    float v = ie[(size_t)(b*L+l)*D+t];
    sv += b1*v; su += b2*v;
  }
  float partial = sv*wc_w[t] + su*wc_w[D+t];
  #pragma unroll
  for (int off=32; off; off>>=1) partial += __shfl_down(partial, off, 64);
  if ((t&63)==0) red[t>>6] = partial;
  __syncthreads();
  if (t==0) alphaS = sigm(red[0]+red[1]+wc_b[0]);
  __syncthreads();
  float al = alphaS;
  float val = ue[(size_t)b*D+t] + al*sv + (1.f-al)*su;
  int mt = b>>4, r = b&15;
  int kf = t>>5, q = (t>>3)&3, j = t&7;
  semb[(size_t)((mt*4+kf)*64 + q*16 + r)*8 + j] = f2bf(val);
}

// ---- K5: scores = seq_emb(512x128) @ v2e[1:]^T, MFMA bf16, f32 out ----
// grid (782, 2): each block = 4 n-tiles (64 cols) x 16 m-tiles (256 rows).
// NORMAL stores (L2 merges partial lines; NT stores caused 1.45x write amplification).
__global__ __launch_bounds__(256) void k_scores(const unsigned short* __restrict__ Afrag,
                                                const float* __restrict__ v2e,
                                                float* __restrict__ out){
  int tid = threadIdx.x;
  int wv = tid >> 6, lane = tid & 63;
  int q = lane >> 4, r = lane & 15;
  int ntile = blockIdx.x*4 + wv;
  int n = ntile*16 + r;
  bool valid = (ntile < NTILES) && (n < NOUT);
  int brow = valid ? (1 + n) : 0;
  const float4* Bf = (const float4*)(v2e + (size_t)brow*D + q*8);
  bf16x8 b[4];
  #pragma unroll
  for (int kf=0; kf<4; kf++){
    float4 lo = Bf[kf*8];      // cols kf*32 + q*8 + 0..3
    float4 hi = Bf[kf*8 + 1];  // cols kf*32 + q*8 + 4..7
    b[kf][0] = (short)f2bf(lo.x); b[kf][1] = (short)f2bf(lo.y);
    b[kf][2] = (short)f2bf(lo.z); b[kf][3] = (short)f2bf(lo.w);
    b[kf][4] = (short)f2bf(hi.x); b[kf][5] = (short)f2bf(hi.y);
    b[kf][6] = (short)f2bf(hi.z); b[kf][7] = (short)f2bf(hi.w);
  }
  const bf16x8* Af = (const bf16x8*)Afrag;
  int mbase = blockIdx.y*16;
  for (int u=0; u<8; ++u){
    int mt0 = mbase + u*2;
    bf16x8 a0[4], a1[4];
    #pragma unroll
    for (int kf=0;kf<4;kf++) a0[kf] = Af[(size_t)(mt0*4+kf)*64 + lane];
    #pragma unroll
    for (int kf=0;kf<4;kf++) a1[kf] = Af[(size_t)((mt0+1)*4+kf)*64 + lane];
    f32x4 acc0 = {0.f,0.f,0.f,0.f};
    f32x4 acc1 = {0.f,0.f,0.f,0.f};
    #pragma unroll
    for (int kf=0;kf<4;kf++)
      acc0 = __builtin_amdgcn_mfma_f32_16x16x32_bf16(a0[kf], b[kf], acc0, 0,0,0);
    #pragma unroll
    for (int kf=0;kf<4;kf++)
      acc1 = __builtin_amdgcn_mfma_f32_16x16x32_bf16(a1[kf], b[kf], acc1, 0,0,0);
    if (valid){
      size_t base0 = (size_t)(mt0*16 + q*4)*NOUT + n;
      out[base0]          = acc0[0];
      out[base0 +   NOUT] = acc0[1];
      out[base0 + 2*NOUT] = acc0[2];
      out[base0 + 3*NOUT] = acc0[3];
      size_t base1 = base0 + (size_t)16*NOUT;
      out[base1]          = acc1[0];
      out[base1 +   NOUT] = acc1[1];
      out[base1 + 2*NOUT] = acc1[2];
      out[base1 + 3*NOUT] = acc1[3];
    }
  }
}

extern "C" void kernel_launch(void* const* d_in, const int* in_sizes, int n_in,
                              void* d_out, int out_size, void* d_ws, size_t ws_size,
                              hipStream_t stream) {
  const int* user     = (const int*)d_in[0];
  const int* seq      = (const int*)d_in[1];
  const int* maskp    = (const int*)d_in[2];
  const int* pos_idx  = (const int*)d_in[4];
  const int* esrc     = (const int*)d_in[5];
  const int* edst     = (const int*)d_in[6];
  const int* item_num = (const int*)d_in[7];
  const float* v2e    = (const float*)d_in[8];
  const float* pos_w  = (const float*)d_in[9];
  const float* Wself  = (const float*)d_in[10];
  const float* Wneigh = (const float*)d_in[11];
  const float* bsage  = (const float*)d_in[12];
  const float* w1     = (const float*)d_in[13];
  const float* w2     = (const float*)d_in[14];
  const float* glu1_w = (const float*)d_in[15];
  const float* glu1_b = (const float*)d_in[16];
  const float* glu2_w = (const float*)d_in[17];
  const float* w3     = (const float*)d_in[18];
  const float* w4     = (const float*)d_in[19];
  const float* glu3_w = (const float*)d_in[20];
  const float* glu3_b = (const float*)d_in[21];
  const float* glu4_w = (const float*)d_in[22];
  const float* wc_w   = (const float*)d_in[23];
  const float* wc_b   = (const float*)d_in[24];
  float* out = (float*)d_out;

  // ---- small scratch in d_ws ----
  char* ws = (char*)d_ws;
  size_t off = 0;
  auto take = [&](size_t n){ size_t o = off; off += (n + 255) & ~(size_t)255; return o; };
  size_t o_cnt    = take(16);
  size_t o_cursor = take((size_t)MAXS*4);
  size_t o_invmap = take((size_t)MAXS*4);
  size_t o_beta1  = take((size_t)BS*L*4);
  size_t o_beta2  = take((size_t)BS*L*4);
  size_t o_semb   = take((size_t)BS*D*2);
  int* counters = (int*)(ws + o_cnt);
  int* cursor   = (int*)(ws + o_cursor);
  int* invmap   = (int*)(ws + o_invmap);
  float* beta1  = (float*)(ws + o_beta1);
  float* beta2  = (float*)(ws + o_beta2);
  unsigned short* semb = (unsigned short*)(ws + o_semb);

  // ---- big scratch in d_out tail (fully consumed before k_scores writes) ----
  char* outb = (char*)d_out;
  size_t to = 84000000;
  auto takeT = [&](size_t n){ size_t o = to; to += (n + 255) & ~(size_t)255; return o; };
  int*            map    = (int*)(outb + takeT((size_t)N_NODES*4));
  int*            bucket = (int*)(outb + takeT((size_t)MAXS*CAP*4));
  float*          neigh  = (float*)(outb + takeT((size_t)MAXS*D*4));
  float*          h1c    = (float*)(outb + takeT((size_t)MAXS*D*4));
  unsigned short* Xcat   = (unsigned short*)(outb + takeT((size_t)BS*L*256*2));
  unsigned short* nh1    = (unsigned short*)(outb + takeT((size_t)BS*L*D*2));
  unsigned short* nh2    = (unsigned short*)(outb + takeT((size_t)BS*L*D*2));
  unsigned short* AU     = (unsigned short*)(outb + takeT((size_t)2*BS*D*2));
  float*          g24    = (float*)(outb + takeT((size_t)2*BS*D*4));
  float*          ie     = (float*)(outb + takeT((size_t)BS*L*D*4));
  float*          ue     = (float*)(outb + takeT((size_t)BS*D*4));
  unsigned short* wT     = (unsigned short*)(outb + takeT((size_t)WT_ELEMS*2));

  k_prep<<<512, 256, 0, stream>>>(w1, w3, glu1_w, glu2_w, glu3_w, glu4_w, wT,
                                  map, cursor, counters);
  k_markcompact<<<(MAXS + 255)/256, 256, 0, stream>>>(seq, user, item_num, map, invmap, counters);
  k_scatter<<<512, 256, 0, stream>>>(esrc, edst, map, cursor, bucket);
  k_neigh<<<MAXS, D, 0, stream>>>(v2e, bucket, cursor, counters, neigh);
  k_h1<<<(MAXS + SL8 - 1)/SL8, D, 0, stream>>>(v2e, neigh, invmap, counters, Wself, Wneigh, bsage, h1c);
  k4a<<<BS, D, 0, stream>>>(user, seq, maskp, pos_idx, item_num, map, h1c, v2e, pos_w,
                            ie, ue, Xcat, AU);
  k4bc<<<384, 256, 0, stream>>>(Xcat, AU, wT, nh1, nh2, g24);
  k4d<<<BS*L/16, 256, 0, stream>>>(nh1, nh2, wT, glu1_b, glu3_b, g24, w2, w4, beta1, beta2);
  k4e<<<BS, D, 0, stream>>>(maskp, beta1, beta2, ie, ue, wc_w, wc_b, semb);
  k_scores<<<dim3(782, 2), 256, 0, stream>>>(semb, v2e, out);
}